// Round 11
// baseline (324.620 us; speedup 1.0000x reference)
//
#include <hip/hip_runtime.h>
#include <hip/hip_bf16.h>
#include <math.h>

// Problem constants (fixed by setup_inputs)
#define SEQ    2048
#define BATCH  4
#define XDIM   16
#define DMODEL 256
#define NHEAD  8
#define DH     32
#define DFF    512
#define NLAYER 2
#define MPOS   1024
#define ROWS   (SEQ*BATCH)   // 8192

#define ATT_SCALE 0.17677669529663687f  // 1/sqrt(32)

typedef __attribute__((ext_vector_type(8))) short bf16x8;  // MFMA A/B frag (4 VGPRs)
typedef __attribute__((ext_vector_type(4))) float f32x4;   // MFMA C/D frag

__device__ __forceinline__ float gelu_exact(float x) {
    return 0.5f * x * (1.0f + erff(x * 0.70710678118654752f));
}

// fp32 -> bf16 (round-to-nearest-even), as raw short
__device__ __forceinline__ short f2bf(float f) {
    unsigned int u = __float_as_uint(f);
    u += 0x7FFFu + ((u >> 16) & 1u);
    return (short)(u >> 16);
}
__device__ __forceinline__ float bf2f(unsigned short u) {
    return __uint_as_float(((unsigned int)u) << 16);
}

// ---------------- encoder + weight casts, ONE launch --------------------------
__global__ __launch_bounds__(256) void encode_cast(
    const float* __restrict__ x, const float* __restrict__ y,
    const float* __restrict__ xw, const float* __restrict__ xb,
    const float* __restrict__ yw, const float* __restrict__ yb,
    float* __restrict__ h, unsigned short* __restrict__ hb,
    const float* __restrict__ s0, const float* __restrict__ s1,
    const float* __restrict__ s2, const float* __restrict__ s3,
    const float* __restrict__ s4,
    unsigned short* __restrict__ d0, unsigned short* __restrict__ d1,
    unsigned short* __restrict__ d2, unsigned short* __restrict__ d3,
    unsigned short* __restrict__ d4)
{
    if (blockIdx.x < ROWS) {
        int row = blockIdx.x;      // s*BATCH + b
        int d   = threadIdx.x;     // 0..255
        int s   = row / BATCH;
        __shared__ float xs[XDIM];
        __shared__ float ys;
        if (d < XDIM) xs[d] = x[(size_t)row*XDIM + d];
        if (d == 0)   ys    = y[row];
        __syncthreads();
        float acc = xb[d];
        #pragma unroll
        for (int k = 0; k < XDIM; ++k) acc = fmaf(xs[k], xw[d*XDIM + k], acc);
        if (s < MPOS) acc += ys * yw[d] + yb[d];
        h[(size_t)row*DMODEL + d]  = acc;
        hb[(size_t)row*DMODEL + d] = (unsigned short)f2bf(acc);
        return;
    }
    int i = (blockIdx.x - ROWS)*256 + threadIdx.x;
    if (i >= 147456) return;
    const float* s; unsigned short* d; int off;
    if      (i <  49152) { s = s0; d = d0; off = i; }
    else if (i <  65536) { s = s1; d = d1; off = i - 49152; }
    else if (i <  98304) { s = s2; d = d2; off = i - 65536; }
    else if (i < 131072) { s = s3; d = d3; off = i - 98304; }
    else                 { s = s4; d = d4; off = i - 131072; }
    float4 a = *(const float4*)(s + (size_t)off*8);
    float4 c = *(const float4*)(s + (size_t)off*8 + 4);
    ushort4 u0, u1;
    u0.x=(unsigned short)f2bf(a.x); u0.y=(unsigned short)f2bf(a.y);
    u0.z=(unsigned short)f2bf(a.z); u0.w=(unsigned short)f2bf(a.w);
    u1.x=(unsigned short)f2bf(c.x); u1.y=(unsigned short)f2bf(c.y);
    u1.z=(unsigned short)f2bf(c.z); u1.w=(unsigned short)f2bf(c.w);
    *(ushort4*)(d + (size_t)off*8)     = u0;
    *(ushort4*)(d + (size_t)off*8 + 4) = u1;
}

#define BK 32
#define LDP 40   // LDS row stride (shorts): 80B = 20 banks -> 2-way only

// ---------------- qkv GEMM 128x128 with fused K/V re-layout (r8) -------------
// N=768 fixed; grid (6, ROWS/128). Blocks 0,1 -> Q; 2,3 -> K; 4,5 -> V.
__global__ __launch_bounds__(256) void gemm_qkv(
    const unsigned short* __restrict__ A, const unsigned short* __restrict__ B,
    const float* __restrict__ bias,
    unsigned short* __restrict__ Qg, unsigned short* __restrict__ Kg,
    unsigned short* __restrict__ Vg, int K)
{
    __shared__ unsigned short As[128][LDP];
    __shared__ unsigned short Bs[128][LDP];
    int tid  = threadIdx.x;
    int w    = tid >> 6, lane = tid & 63;
    int col  = lane & 15, quad = lane >> 4;
    int wm   = (w >> 1) * 64, wn = (w & 1) * 64;
    int m0   = blockIdx.y * 128, n0 = blockIdx.x * 128;
    int lrow = tid >> 2, lch = (tid & 3) * 8;

    f32x4 acc[4][4];
    #pragma unroll
    for (int i = 0; i < 4; ++i)
        #pragma unroll
        for (int j = 0; j < 4; ++j) acc[i][j] = (f32x4){0.f,0.f,0.f,0.f};

    for (int k0 = 0; k0 < K; k0 += BK) {
        __syncthreads();
        *(uint4*)&As[lrow   ][lch] = *(const uint4*)(A + (size_t)(m0+lrow   )*K + k0 + lch);
        *(uint4*)&As[lrow+64][lch] = *(const uint4*)(A + (size_t)(m0+lrow+64)*K + k0 + lch);
        *(uint4*)&Bs[lrow   ][lch] = *(const uint4*)(B + (size_t)(n0+lrow   )*K + k0 + lch);
        *(uint4*)&Bs[lrow+64][lch] = *(const uint4*)(B + (size_t)(n0+lrow+64)*K + k0 + lch);
        __syncthreads();
        bf16x8 af[4], bfr[4];
        #pragma unroll
        for (int i = 0; i < 4; ++i) af[i]  = *(const bf16x8*)&As[wm + i*16 + col][quad*8];
        #pragma unroll
        for (int j = 0; j < 4; ++j) bfr[j] = *(const bf16x8*)&Bs[wn + j*16 + col][quad*8];
        #pragma unroll
        for (int i = 0; i < 4; ++i)
            #pragma unroll
            for (int j = 0; j < 4; ++j)
                acc[i][j] = __builtin_amdgcn_mfma_f32_16x16x32_bf16(bfr[j], af[i], acc[i][j], 0, 0, 0);
    }

    int region = n0 >> 8;   // 0=Q, 1=K, 2=V (uniform per block)
    #pragma unroll
    for (int i = 0; i < 4; ++i) {
        int m = m0 + wm + i*16 + col;
        int s = m >> 2, bidx = m & 3;
        #pragma unroll
        for (int j = 0; j < 4; ++j) {
            int ng = n0 + wn + j*16 + quad*4;
            float4 bi = *(const float4*)&bias[ng];
            ushort4 u;
            u.x=(unsigned short)f2bf(acc[i][j][0] + bi.x);
            u.y=(unsigned short)f2bf(acc[i][j][1] + bi.y);
            u.z=(unsigned short)f2bf(acc[i][j][2] + bi.z);
            u.w=(unsigned short)f2bf(acc[i][j][3] + bi.w);
            int np = ng - (region << 8);
            int hh = np >> 5, d = np & 31;
            int bh = bidx*NHEAD + hh;
            if (region == 0)
                *(ushort4*)(Qg + ((size_t)(bh*SEQ + s))*DH + d) = u;
            else if (region == 1)
                *(ushort4*)(Kg + ((size_t)(bh*SEQ + s))*DH + d) = u;
            else {
                Vg[((size_t)(bh*DH + d    ))*SEQ + s] = u.x;
                Vg[((size_t)(bh*DH + d + 1))*SEQ + s] = u.y;
                Vg[((size_t)(bh*DH + d + 2))*SEQ + s] = u.z;
                Vg[((size_t)(bh*DH + d + 3))*SEQ + s] = u.w;
            }
        }
    }
}

// ------- GEMM (N=256) + residual + LayerNorm fused, swapped epilogue (r8) ----
__global__ __launch_bounds__(256) void gemm_ln(
    const unsigned short* __restrict__ A, const unsigned short* __restrict__ B,
    const float* __restrict__ bias, const float* __restrict__ g,
    const float* __restrict__ beta, float* __restrict__ h,
    unsigned short* __restrict__ hb, int K)
{
    __shared__ unsigned short As[32][LDP];
    __shared__ unsigned short Bs[256][LDP];
    __shared__ float sP[2][32], qP[2][32];
    int tid  = threadIdx.x;
    int w    = tid >> 6, lane = tid & 63;
    int col  = lane & 15, quad = lane >> 4;
    int wr   = w >> 1, wc = w & 1;
    int m0   = blockIdx.x * 32;
    int brow = tid >> 2, bch = (tid & 3) * 8;

    f32x4 acc[8];
    #pragma unroll
    for (int j = 0; j < 8; ++j) acc[j] = (f32x4){0.f,0.f,0.f,0.f};

    for (int k0 = 0; k0 < K; k0 += BK) {
        __syncthreads();
        if (tid < 128)
            *(uint4*)&As[tid>>2][bch] = *(const uint4*)(A + (size_t)(m0+(tid>>2))*K + k0 + bch);
        #pragma unroll
        for (int rr = 0; rr < 4; ++rr)
            *(uint4*)&Bs[brow + rr*64][bch] = *(const uint4*)(B + (size_t)(brow + rr*64)*K + k0 + bch);
        __syncthreads();
        bf16x8 af = *(const bf16x8*)&As[16*wr + col][quad*8];
        #pragma unroll
        for (int j = 0; j < 8; ++j) {
            bf16x8 bfr = *(const bf16x8*)&Bs[128*wc + j*16 + col][quad*8];
            acc[j] = __builtin_amdgcn_mfma_f32_16x16x32_bf16(bfr, af, acc[j], 0, 0, 0);
        }
    }

    int m = m0 + 16*wr + col;
    float v[8][4];
    float s = 0.f, q = 0.f;
    #pragma unroll
    for (int j = 0; j < 8; ++j) {
        int n = 128*wc + j*16 + quad*4;
        float4 bi = *(const float4*)&bias[n];
        float4 hv = *(const float4*)&h[(size_t)m*DMODEL + n];
        float val0 = acc[j][0] + bi.x + hv.x;
        float val1 = acc[j][1] + bi.y + hv.y;
        float val2 = acc[j][2] + bi.z + hv.z;
        float val3 = acc[j][3] + bi.w + hv.w;
        v[j][0]=val0; v[j][1]=val1; v[j][2]=val2; v[j][3]=val3;
        s += (val0+val1) + (val2+val3);
        q += (val0*val0 + val1*val1) + (val2*val2 + val3*val3);
    }
    s += __shfl_xor(s, 16, 64); s += __shfl_xor(s, 32, 64);
    q += __shfl_xor(q, 16, 64); q += __shfl_xor(q, 32, 64);
    if (quad == 0) { sP[wc][16*wr + col] = s; qP[wc][16*wr + col] = q; }
    __syncthreads();
    float st = sP[0][16*wr + col] + sP[1][16*wr + col];
    float qt = qP[0][16*wr + col] + qP[1][16*wr + col];
    float mu   = st * (1.0f/DMODEL);
    float var  = qt * (1.0f/DMODEL) - mu*mu;
    float rstd = rsqrtf(var + 1e-5f);
    #pragma unroll
    for (int j = 0; j < 8; ++j) {
        int n = 128*wc + j*16 + quad*4;
        float4 gv = *(const float4*)&g[n];
        float4 bv = *(const float4*)&beta[n];
        float4 o;
        o.x = (v[j][0]-mu)*rstd*gv.x + bv.x;
        o.y = (v[j][1]-mu)*rstd*gv.y + bv.y;
        o.z = (v[j][2]-mu)*rstd*gv.z + bv.z;
        o.w = (v[j][3]-mu)*rstd*gv.w + bv.w;
        *(float4*)&h[(size_t)m*DMODEL + n] = o;
        ushort4 u;
        u.x=(unsigned short)f2bf(o.x); u.y=(unsigned short)f2bf(o.y);
        u.z=(unsigned short)f2bf(o.z); u.w=(unsigned short)f2bf(o.w);
        *(ushort4*)(hb + (size_t)m*DMODEL + n) = u;
    }
}

// ------- fused FFN: h = LN(h + gelu(h@W1^T + b1) @ W2^T + b2) ----------------
// BM=16 rows/block (512 blocks). Phase 1: ff (16x512) built in LDS via 4
// n-tiles x 8 k-iters (2 MFMA/wave/iter). Phase 2: K=512 stream of W2
// (16 k-iters, 4 MFMA/wave/iter) + residual + LN epilogue (r10-verified).
__global__ __launch_bounds__(256) void gemm_ffn(
    const unsigned short* __restrict__ A,   // hb
    const unsigned short* __restrict__ W1, const float* __restrict__ b1,
    const unsigned short* __restrict__ W2, const float* __restrict__ b2,
    const float* __restrict__ g, const float* __restrict__ beta,
    float* __restrict__ h, unsigned short* __restrict__ hb)
{
    __shared__ unsigned short As[16][280];   // stride 280: 140 dw %32=12 -> spread
    __shared__ unsigned short Fs[16][536];   // stride 536: 268 dw %32=12 -> spread
    __shared__ unsigned short Bs[256][LDP];
    __shared__ float sP[4][16], qP[4][16];
    int tid  = threadIdx.x;
    int w    = tid >> 6, lane = tid & 63;
    int col  = lane & 15, quad = lane >> 4;
    int m0   = blockIdx.x * 16;

    // stage full 16x256 A tile once
    {
        int row = tid >> 4, c0 = (tid & 15) * 16;
        *(uint4*)&As[row][c0]   = *(const uint4*)(A + (size_t)(m0+row)*DMODEL + c0);
        *(uint4*)&As[row][c0+8] = *(const uint4*)(A + (size_t)(m0+row)*DMODEL + c0 + 8);
    }

    // ---- phase 1 ----
    int brow = tid >> 1, bch1 = (tid & 1) * 16;
    for (int nt = 0; nt < 4; ++nt) {
        f32x4 a2[2];
        a2[0] = (f32x4){0.f,0.f,0.f,0.f};
        a2[1] = (f32x4){0.f,0.f,0.f,0.f};
        for (int it = 0; it < 8; ++it) {
            __syncthreads();
            const unsigned short* wp = W1 + (size_t)(nt*128 + brow)*DMODEL + it*32 + bch1;
            *(uint4*)&Bs[brow][bch1]     = *(const uint4*)wp;
            *(uint4*)&Bs[brow][bch1 + 8] = *(const uint4*)(wp + 8);
            __syncthreads();
            bf16x8 af = *(const bf16x8*)&As[col][it*32 + quad*8];
            #pragma unroll
            for (int j = 0; j < 2; ++j) {
                bf16x8 bfr = *(const bf16x8*)&Bs[(2*w+j)*16 + col][quad*8];
                a2[j] = __builtin_amdgcn_mfma_f32_16x16x32_bf16(bfr, af, a2[j], 0, 0, 0);
            }
        }
        #pragma unroll
        for (int j = 0; j < 2; ++j) {
            int n = nt*128 + (2*w+j)*16 + quad*4;
            float4 bi = *(const float4*)&b1[n];
            ushort4 u;
            u.x = (unsigned short)f2bf(gelu_exact(a2[j][0] + bi.x));
            u.y = (unsigned short)f2bf(gelu_exact(a2[j][1] + bi.y));
            u.z = (unsigned short)f2bf(gelu_exact(a2[j][2] + bi.z));
            u.w = (unsigned short)f2bf(gelu_exact(a2[j][3] + bi.w));
            *(ushort4*)&Fs[col][n] = u;
        }
    }

    // ---- phase 2 ----
    f32x4 acc[4];
    #pragma unroll
    for (int j = 0; j < 4; ++j) acc[j] = (f32x4){0.f,0.f,0.f,0.f};
    for (int it = 0; it < 16; ++it) {
        __syncthreads();
        const unsigned short* wp = W2 + (size_t)tid*DFF + it*32;
        *(uint4*)&Bs[tid][0]  = *(const uint4*)wp;
        *(uint4*)&Bs[tid][8]  = *(const uint4*)(wp + 8);
        *(uint4*)&Bs[tid][16] = *(const uint4*)(wp + 16);
        *(uint4*)&Bs[tid][24] = *(const uint4*)(wp + 24);
        __syncthreads();
        bf16x8 af = *(const bf16x8*)&Fs[col][it*32 + quad*8];
        #pragma unroll
        for (int j = 0; j < 4; ++j) {
            bf16x8 bfr = *(const bf16x8*)&Bs[64*w + j*16 + col][quad*8];
            acc[j] = __builtin_amdgcn_mfma_f32_16x16x32_bf16(bfr, af, acc[j], 0, 0, 0);
        }
    }

    int m = m0 + col;
    float v[4][4];
    float s = 0.f, q = 0.f;
    #pragma unroll
    for (int j = 0; j < 4; ++j) {
        int n = 64*w + j*16 + quad*4;
        float4 bi = *(const float4*)&b2[n];
        float4 hv = *(const float4*)&h[(size_t)m*DMODEL + n];
        float val0 = acc[j][0] + bi.x + hv.x;
        float val1 = acc[j][1] + bi.y + hv.y;
        float val2 = acc[j][2] + bi.z + hv.z;
        float val3 = acc[j][3] + bi.w + hv.w;
        v[j][0]=val0; v[j][1]=val1; v[j][2]=val2; v[j][3]=val3;
        s += (val0+val1) + (val2+val3);
        q += (val0*val0 + val1*val1) + (val2*val2 + val3*val3);
    }
    s += __shfl_xor(s, 16, 64); s += __shfl_xor(s, 32, 64);
    q += __shfl_xor(q, 16, 64); q += __shfl_xor(q, 32, 64);
    if (quad == 0) { sP[w][col] = s; qP[w][col] = q; }
    __syncthreads();
    float st = (sP[0][col] + sP[1][col]) + (sP[2][col] + sP[3][col]);
    float qt = (qP[0][col] + qP[1][col]) + (qP[2][col] + qP[3][col]);
    float mu   = st * (1.0f/DMODEL);
    float var  = qt * (1.0f/DMODEL) - mu*mu;
    float rstd = rsqrtf(var + 1e-5f);
    #pragma unroll
    for (int j = 0; j < 4; ++j) {
        int n = 64*w + j*16 + quad*4;
        float4 gv = *(const float4*)&g[n];
        float4 bv = *(const float4*)&beta[n];
        float4 o;
        o.x = (v[j][0]-mu)*rstd*gv.x + bv.x;
        o.y = (v[j][1]-mu)*rstd*gv.y + bv.y;
        o.z = (v[j][2]-mu)*rstd*gv.z + bv.z;
        o.w = (v[j][3]-mu)*rstd*gv.w + bv.w;
        *(float4*)&h[(size_t)m*DMODEL + n] = o;
        ushort4 u;
        u.x=(unsigned short)f2bf(o.x); u.y=(unsigned short)f2bf(o.y);
        u.z=(unsigned short)f2bf(o.z); u.w=(unsigned short)f2bf(o.w);
        *(ushort4*)(hb + (size_t)m*DMODEL + n) = u;
    }
}

// ------- head: out = gelu(A@W1^T + b1) . w2 + b2, swapped epilogue (r8) ------
__global__ __launch_bounds__(256) void gemm_head(
    const unsigned short* __restrict__ A, const unsigned short* __restrict__ B,
    const float* __restrict__ b1, const float* __restrict__ w2,
    const float* __restrict__ b2, float* __restrict__ out, int K)
{
    __shared__ unsigned short As[16][LDP];
    __shared__ unsigned short Bs[512][LDP];
    __shared__ float dP[4][16];
    int tid  = threadIdx.x;
    int w    = tid >> 6, lane = tid & 63;
    int col  = lane & 15, quad = lane >> 4;
    int m0   = blockIdx.x * 16;
    int brow = tid >> 2, bch = (tid & 3) * 8;

    f32x4 acc[8];
    #pragma unroll
    for (int j = 0; j < 8; ++j) acc[j] = (f32x4){0.f,0.f,0.f,0.f};

    for (int k0 = 0; k0 < K; k0 += BK) {
        __syncthreads();
        if (tid < 64)
            *(uint4*)&As[tid>>2][bch] = *(const uint4*)(A + (size_t)(m0+(tid>>2))*K + k0 + bch);
        #pragma unroll
        for (int rr = 0; rr < 8; ++rr)
            *(uint4*)&Bs[brow + rr*64][bch] = *(const uint4*)(B + (size_t)(brow + rr*64)*K + k0 + bch);
        __syncthreads();
        bf16x8 af = *(const bf16x8*)&As[col][quad*8];
        #pragma unroll
        for (int j = 0; j < 8; ++j) {
            bf16x8 bfr = *(const bf16x8*)&Bs[128*w + j*16 + col][quad*8];
            acc[j] = __builtin_amdgcn_mfma_f32_16x16x32_bf16(bfr, af, acc[j], 0, 0, 0);
        }
    }

    float s = 0.f;
    #pragma unroll
    for (int j = 0; j < 8; ++j) {
        int n = 128*w + j*16 + quad*4;
        float4 b1v = *(const float4*)&b1[n];
        float4 w2v = *(const float4*)&w2[n];
        s += gelu_exact(acc[j][0] + b1v.x) * w2v.x;
        s += gelu_exact(acc[j][1] + b1v.y) * w2v.y;
        s += gelu_exact(acc[j][2] + b1v.z) * w2v.z;
        s += gelu_exact(acc[j][3] + b1v.w) * w2v.w;
    }
    s += __shfl_xor(s, 16, 64); s += __shfl_xor(s, 32, 64);
    if (quad == 0) dP[w][col] = s;
    __syncthreads();
    if (tid < 16)
        out[m0 + tid] = dP[0][tid] + dP[1][tid] + dP[2][tid] + dP[3][tid] + b2[0];
}

// ---------------- MFMA flash attention, transposed flow (r8) -----------------
__global__ __launch_bounds__(256) void attn_mfma(
    const unsigned short* __restrict__ Qg,
    const unsigned short* __restrict__ Kg,
    const unsigned short* __restrict__ Vg,
    unsigned short* __restrict__ o)           // bf16 [s*B+b][256]
{
    const int qt = blockIdx.x;
    const int h  = blockIdx.y;
    const int b  = blockIdx.z;
    const int q0 = qt * 64;
    const int tid  = threadIdx.x;
    const int w    = tid >> 6;
    const int lane = tid & 63;
    const int col  = lane & 15;
    const int quad = lane >> 4;
    const int bh   = b*NHEAD + h;

    __shared__ unsigned short Kt[64][40];     // [key][d]
    __shared__ unsigned short Vt[32][72];     // [d][key]
    __shared__ unsigned short Pt[4][16][72];  // per-wave P [q][key]

    const int q = q0 + 16*w + col;
    bf16x8 qf = *(const bf16x8*)(Qg + ((size_t)(bh*SEQ + q))*DH + quad*8);

    f32x4 O0 = {0.f,0.f,0.f,0.f};
    f32x4 O1 = {0.f,0.f,0.f,0.f};
    float lsum = 0.f;

    const int kRow = tid >> 2, kCh = (tid & 3) * 8;
    const int vD   = tid >> 3, vCh = (tid & 7) * 8;

    const int nT = 16 + ((q0 >= MPOS) ? 1 : 0);
    for (int kt = 0; kt < nT; ++kt) {
        const bool self = (kt == 16);
        const int  k0   = self ? q0 : kt*64;
        __syncthreads();
        *(uint4*)&Kt[kRow][kCh] = *(const uint4*)(Kg + ((size_t)(bh*SEQ + k0 + kRow))*DH + kCh);
        *(uint4*)&Vt[vD][vCh]   = *(const uint4*)(Vg + ((size_t)(bh*DH + vD))*SEQ + k0 + vCh);
        __syncthreads();

        #pragma unroll
        for (int mt = 0; mt < 4; ++mt) {
            bf16x8 kf = *(const bf16x8*)&Kt[mt*16 + col][quad*8];
            f32x4 st = {0.f,0.f,0.f,0.f};
            st = __builtin_amdgcn_mfma_f32_16x16x32_bf16(kf, qf, st, 0, 0, 0);
            ushort4 pw;
            #pragma unroll
            for (int i = 0; i < 4; ++i) {
                float p = __expf(st[i]*ATT_SCALE);
                if (self && (mt*16 + quad*4 + i != 16*w + col)) p = 0.f;
                unsigned short us = (unsigned short)f2bf(p);
                ((unsigned short*)&pw)[i] = us;
                lsum += bf2f(us);
            }
            *(ushort4*)&Pt[w][col][mt*16 + quad*4] = pw;
        }
        #pragma unroll
        for (int c = 0; c < 2; ++c) {
            bf16x8 pf = *(const bf16x8*)&Pt[w][col][c*32 + quad*8];
            bf16x8 v0 = *(const bf16x8*)&Vt[col     ][c*32 + quad*8];
            bf16x8 v1 = *(const bf16x8*)&Vt[col + 16][c*32 + quad*8];
            O0 = __builtin_amdgcn_mfma_f32_16x16x32_bf16(v0, pf, O0, 0, 0, 0);
            O1 = __builtin_amdgcn_mfma_f32_16x16x32_bf16(v1, pf, O1, 0, 0, 0);
        }
    }

    lsum += __shfl_xor(lsum, 16, 64);
    lsum += __shfl_xor(lsum, 32, 64);
    float inv = 1.0f / lsum;
    ushort4 u0, u1;
    #pragma unroll
    for (int i = 0; i < 4; ++i) {
        ((unsigned short*)&u0)[i] = (unsigned short)f2bf(O0[i]*inv);
        ((unsigned short*)&u1)[i] = (unsigned short)f2bf(O1[i]*inv);
    }
    unsigned short* op = o + ((size_t)(q*BATCH + b))*DMODEL + h*DH;
    *(ushort4*)(op + quad*4)      = u0;
    *(ushort4*)(op + 16 + quad*4) = u1;
}

extern "C" void kernel_launch(void* const* d_in, const int* in_sizes, int n_in,
                              void* d_out, int out_size, void* d_ws, size_t ws_size,
                              hipStream_t stream)
{
    const float* x        = (const float*)d_in[0];
    const float* y        = (const float*)d_in[1];
    const float* xenc_w   = (const float*)d_in[3];
    const float* xenc_b   = (const float*)d_in[4];
    const float* yenc_w   = (const float*)d_in[5];
    const float* yenc_b   = (const float*)d_in[6];
    const float* in_proj_w  = (const float*)d_in[7];
    const float* in_proj_b  = (const float*)d_in[8];
    const float* out_proj_w = (const float*)d_in[9];
    const float* out_proj_b = (const float*)d_in[10];
    const float* ln1_g    = (const float*)d_in[11];
    const float* ln1_b    = (const float*)d_in[12];
    const float* lin1_w   = (const float*)d_in[13];
    const float* lin1_b   = (const float*)d_in[14];
    const float* lin2_w   = (const float*)d_in[15];
    const float* lin2_b   = (const float*)d_in[16];
    const float* ln2_g    = (const float*)d_in[17];
    const float* ln2_b    = (const float*)d_in[18];
    const float* head_w1  = (const float*)d_in[19];
    const float* head_b1  = (const float*)d_in[20];
    const float* head_w2  = (const float*)d_in[21];
    const float* head_b2  = (const float*)d_in[22];
    float* out = (float*)d_out;

    // ---- workspace layout ----
    float* ws  = (float*)d_ws;
    float* h    = ws;                                           // 2M f32
    unsigned short* hb    = (unsigned short*)(h + (size_t)ROWS*DMODEL);  // 2M bf16
    unsigned short* attb  = hb    + (size_t)ROWS*DMODEL;        // 2M bf16
    unsigned short* Qg    = attb  + (size_t)ROWS*DMODEL;        // 2M bf16
    unsigned short* Kg    = Qg    + (size_t)BATCH*NHEAD*SEQ*DH; // 2M bf16
    unsigned short* Vg    = Kg    + (size_t)BATCH*NHEAD*SEQ*DH; // 2M bf16
    unsigned short* Wqkv  = Vg    + (size_t)BATCH*NHEAD*SEQ*DH; // weights bf16
    unsigned short* Wout  = Wqkv  + (size_t)NLAYER*3*DMODEL*DMODEL;
    unsigned short* Wl1   = Wout  + (size_t)NLAYER*DMODEL*DMODEL;
    unsigned short* Wl2   = Wl1   + (size_t)NLAYER*DFF*DMODEL;
    unsigned short* Wh1   = Wl2   + (size_t)NLAYER*DMODEL*DFF;

    encode_cast<<<ROWS + 576, 256, 0, stream>>>(
        x, y, xenc_w, xenc_b, yenc_w, yenc_b, h, hb,
        in_proj_w, out_proj_w, lin1_w, lin2_w, head_w1,
        Wqkv, Wout, Wl1, Wl2, Wh1);

    for (int l = 0; l < NLAYER; ++l) {
        gemm_qkv<<<dim3(6, ROWS/128), 256, 0, stream>>>(
            hb, Wqkv + (size_t)l*3*DMODEL*DMODEL, in_proj_b + l*3*DMODEL,
            Qg, Kg, Vg, DMODEL);
        attn_mfma<<<dim3(SEQ/64, NHEAD, BATCH), 256, 0, stream>>>(Qg, Kg, Vg, attb);
        gemm_ln<<<ROWS/32, 256, 0, stream>>>(
            attb, Wout + (size_t)l*DMODEL*DMODEL, out_proj_b + l*DMODEL,
            ln1_g + l*DMODEL, ln1_b + l*DMODEL, h, hb, DMODEL);
        gemm_ffn<<<ROWS/16, 256, 0, stream>>>(
            hb, Wl1 + (size_t)l*DFF*DMODEL, lin1_b + l*DFF,
            Wl2 + (size_t)l*DMODEL*DFF, lin2_b + l*DMODEL,
            ln2_g + l*DMODEL, ln2_b + l*DMODEL, h, hb);
    }

    const int QROWS = (SEQ - MPOS) * BATCH;  // 4096
    gemm_head<<<QROWS/16, 256, 0, stream>>>(
        hb + (size_t)MPOS*BATCH*DMODEL, Wh1, head_b1, head_w2, head_b2, out, DMODEL);
}

// Round 12
// 311.620 us; speedup vs baseline: 1.0417x; 1.0417x over previous
//
#include <hip/hip_runtime.h>
#include <hip/hip_bf16.h>
#include <math.h>

// Problem constants (fixed by setup_inputs)
#define SEQ    2048
#define BATCH  4
#define XDIM   16
#define DMODEL 256
#define NHEAD  8
#define DH     32
#define DFF    512
#define NLAYER 2
#define MPOS   1024
#define ROWS   (SEQ*BATCH)   // 8192

#define ATT_SCALE 0.17677669529663687f  // 1/sqrt(32)

typedef __attribute__((ext_vector_type(8))) short bf16x8;  // MFMA A/B frag (4 VGPRs)
typedef __attribute__((ext_vector_type(4))) float f32x4;   // MFMA C/D frag

__device__ __forceinline__ float gelu_exact(float x) {
    return 0.5f * x * (1.0f + erff(x * 0.70710678118654752f));
}

// fp32 -> bf16 (round-to-nearest-even), as raw short
__device__ __forceinline__ short f2bf(float f) {
    unsigned int u = __float_as_uint(f);
    u += 0x7FFFu + ((u >> 16) & 1u);
    return (short)(u >> 16);
}
__device__ __forceinline__ float bf2f(unsigned short u) {
    return __uint_as_float(((unsigned int)u) << 16);
}

// ---------------- encoder + weight casts, ONE launch --------------------------
__global__ __launch_bounds__(256) void encode_cast(
    const float* __restrict__ x, const float* __restrict__ y,
    const float* __restrict__ xw, const float* __restrict__ xb,
    const float* __restrict__ yw, const float* __restrict__ yb,
    float* __restrict__ h, unsigned short* __restrict__ hb,
    const float* __restrict__ s0, const float* __restrict__ s1,
    const float* __restrict__ s2, const float* __restrict__ s3,
    const float* __restrict__ s4,
    unsigned short* __restrict__ d0, unsigned short* __restrict__ d1,
    unsigned short* __restrict__ d2, unsigned short* __restrict__ d3,
    unsigned short* __restrict__ d4)
{
    if (blockIdx.x < ROWS) {
        int row = blockIdx.x;      // s*BATCH + b
        int d   = threadIdx.x;     // 0..255
        int s   = row / BATCH;
        __shared__ float xs[XDIM];
        __shared__ float ys;
        if (d < XDIM) xs[d] = x[(size_t)row*XDIM + d];
        if (d == 0)   ys    = y[row];
        __syncthreads();
        float acc = xb[d];
        #pragma unroll
        for (int k = 0; k < XDIM; ++k) acc = fmaf(xs[k], xw[d*XDIM + k], acc);
        if (s < MPOS) acc += ys * yw[d] + yb[d];
        h[(size_t)row*DMODEL + d]  = acc;
        hb[(size_t)row*DMODEL + d] = (unsigned short)f2bf(acc);
        return;
    }
    int i = (blockIdx.x - ROWS)*256 + threadIdx.x;
    if (i >= 147456) return;
    const float* s; unsigned short* d; int off;
    if      (i <  49152) { s = s0; d = d0; off = i; }
    else if (i <  65536) { s = s1; d = d1; off = i - 49152; }
    else if (i <  98304) { s = s2; d = d2; off = i - 65536; }
    else if (i < 131072) { s = s3; d = d3; off = i - 98304; }
    else                 { s = s4; d = d4; off = i - 131072; }
    float4 a = *(const float4*)(s + (size_t)off*8);
    float4 c = *(const float4*)(s + (size_t)off*8 + 4);
    ushort4 u0, u1;
    u0.x=(unsigned short)f2bf(a.x); u0.y=(unsigned short)f2bf(a.y);
    u0.z=(unsigned short)f2bf(a.z); u0.w=(unsigned short)f2bf(a.w);
    u1.x=(unsigned short)f2bf(c.x); u1.y=(unsigned short)f2bf(c.y);
    u1.z=(unsigned short)f2bf(c.z); u1.w=(unsigned short)f2bf(c.w);
    *(ushort4*)(d + (size_t)off*8)     = u0;
    *(ushort4*)(d + (size_t)off*8 + 4) = u1;
}

// ---------------- bf16 MFMA GEMM 128x128, swapped epilogue (ff1) -------------
// MFMA(bfr, af): D row = n (quad*4+r), D col = m (col). Lane stores 4
// consecutive n for one m -> ushort4.
#define BK 32
#define LDP 40   // LDS row stride (shorts): 80B = 20 banks -> 2-way only
__global__ __launch_bounds__(256) void gemm128(
    const unsigned short* __restrict__ A, const unsigned short* __restrict__ B,
    const float* __restrict__ bias, unsigned short* __restrict__ Cb,
    int N, int K, int doGelu)
{
    __shared__ unsigned short As[128][LDP];
    __shared__ unsigned short Bs[128][LDP];
    int tid  = threadIdx.x;
    int w    = tid >> 6, lane = tid & 63;
    int col  = lane & 15, quad = lane >> 4;
    int wm   = (w >> 1) * 64, wn = (w & 1) * 64;
    int m0   = blockIdx.y * 128, n0 = blockIdx.x * 128;
    int lrow = tid >> 2, lch = (tid & 3) * 8;

    f32x4 acc[4][4];
    #pragma unroll
    for (int i = 0; i < 4; ++i)
        #pragma unroll
        for (int j = 0; j < 4; ++j) acc[i][j] = (f32x4){0.f,0.f,0.f,0.f};

    for (int k0 = 0; k0 < K; k0 += BK) {
        __syncthreads();
        *(uint4*)&As[lrow   ][lch] = *(const uint4*)(A + (size_t)(m0+lrow   )*K + k0 + lch);
        *(uint4*)&As[lrow+64][lch] = *(const uint4*)(A + (size_t)(m0+lrow+64)*K + k0 + lch);
        *(uint4*)&Bs[lrow   ][lch] = *(const uint4*)(B + (size_t)(n0+lrow   )*K + k0 + lch);
        *(uint4*)&Bs[lrow+64][lch] = *(const uint4*)(B + (size_t)(n0+lrow+64)*K + k0 + lch);
        __syncthreads();
        bf16x8 af[4], bfr[4];
        #pragma unroll
        for (int i = 0; i < 4; ++i) af[i]  = *(const bf16x8*)&As[wm + i*16 + col][quad*8];
        #pragma unroll
        for (int j = 0; j < 4; ++j) bfr[j] = *(const bf16x8*)&Bs[wn + j*16 + col][quad*8];
        #pragma unroll
        for (int i = 0; i < 4; ++i)
            #pragma unroll
            for (int j = 0; j < 4; ++j)
                acc[i][j] = __builtin_amdgcn_mfma_f32_16x16x32_bf16(bfr[j], af[i], acc[i][j], 0, 0, 0);
    }

    #pragma unroll
    for (int i = 0; i < 4; ++i) {
        int m = m0 + wm + i*16 + col;
        #pragma unroll
        for (int j = 0; j < 4; ++j) {
            int n = n0 + wn + j*16 + quad*4;
            float4 bi = *(const float4*)&bias[n];
            float v0 = acc[i][j][0] + bi.x, v1 = acc[i][j][1] + bi.y;
            float v2 = acc[i][j][2] + bi.z, v3 = acc[i][j][3] + bi.w;
            if (doGelu) { v0=gelu_exact(v0); v1=gelu_exact(v1); v2=gelu_exact(v2); v3=gelu_exact(v3); }
            ushort4 u;
            u.x=(unsigned short)f2bf(v0); u.y=(unsigned short)f2bf(v1);
            u.z=(unsigned short)f2bf(v2); u.w=(unsigned short)f2bf(v3);
            *(ushort4*)(Cb + (size_t)m*N + n) = u;
        }
    }
}

// ---------------- qkv GEMM with fused K/V re-layout --------------------------
// N=768 fixed; grid (6, ROWS/128). Blocks 0,1 -> Q; 2,3 -> K; 4,5 -> V.
// Q,K written [b][h][s][d] (ushort4); V written transposed [b][h][d][s].
__global__ __launch_bounds__(256) void gemm_qkv(
    const unsigned short* __restrict__ A, const unsigned short* __restrict__ B,
    const float* __restrict__ bias,
    unsigned short* __restrict__ Qg, unsigned short* __restrict__ Kg,
    unsigned short* __restrict__ Vg, int K)
{
    __shared__ unsigned short As[128][LDP];
    __shared__ unsigned short Bs[128][LDP];
    int tid  = threadIdx.x;
    int w    = tid >> 6, lane = tid & 63;
    int col  = lane & 15, quad = lane >> 4;
    int wm   = (w >> 1) * 64, wn = (w & 1) * 64;
    int m0   = blockIdx.y * 128, n0 = blockIdx.x * 128;
    int lrow = tid >> 2, lch = (tid & 3) * 8;

    f32x4 acc[4][4];
    #pragma unroll
    for (int i = 0; i < 4; ++i)
        #pragma unroll
        for (int j = 0; j < 4; ++j) acc[i][j] = (f32x4){0.f,0.f,0.f,0.f};

    for (int k0 = 0; k0 < K; k0 += BK) {
        __syncthreads();
        *(uint4*)&As[lrow   ][lch] = *(const uint4*)(A + (size_t)(m0+lrow   )*K + k0 + lch);
        *(uint4*)&As[lrow+64][lch] = *(const uint4*)(A + (size_t)(m0+lrow+64)*K + k0 + lch);
        *(uint4*)&Bs[lrow   ][lch] = *(const uint4*)(B + (size_t)(n0+lrow   )*K + k0 + lch);
        *(uint4*)&Bs[lrow+64][lch] = *(const uint4*)(B + (size_t)(n0+lrow+64)*K + k0 + lch);
        __syncthreads();
        bf16x8 af[4], bfr[4];
        #pragma unroll
        for (int i = 0; i < 4; ++i) af[i]  = *(const bf16x8*)&As[wm + i*16 + col][quad*8];
        #pragma unroll
        for (int j = 0; j < 4; ++j) bfr[j] = *(const bf16x8*)&Bs[wn + j*16 + col][quad*8];
        #pragma unroll
        for (int i = 0; i < 4; ++i)
            #pragma unroll
            for (int j = 0; j < 4; ++j)
                acc[i][j] = __builtin_amdgcn_mfma_f32_16x16x32_bf16(bfr[j], af[i], acc[i][j], 0, 0, 0);
    }

    int region = n0 >> 8;   // 0=Q, 1=K, 2=V (uniform per block)
    #pragma unroll
    for (int i = 0; i < 4; ++i) {
        int m = m0 + wm + i*16 + col;
        int s = m >> 2, bidx = m & 3;
        #pragma unroll
        for (int j = 0; j < 4; ++j) {
            int ng = n0 + wn + j*16 + quad*4;
            float4 bi = *(const float4*)&bias[ng];
            ushort4 u;
            u.x=(unsigned short)f2bf(acc[i][j][0] + bi.x);
            u.y=(unsigned short)f2bf(acc[i][j][1] + bi.y);
            u.z=(unsigned short)f2bf(acc[i][j][2] + bi.z);
            u.w=(unsigned short)f2bf(acc[i][j][3] + bi.w);
            int np = ng - (region << 8);
            int hh = np >> 5, d = np & 31;
            int bh = bidx*NHEAD + hh;
            if (region == 0)
                *(ushort4*)(Qg + ((size_t)(bh*SEQ + s))*DH + d) = u;
            else if (region == 1)
                *(ushort4*)(Kg + ((size_t)(bh*SEQ + s))*DH + d) = u;
            else {
                Vg[((size_t)(bh*DH + d    ))*SEQ + s] = u.x;
                Vg[((size_t)(bh*DH + d + 1))*SEQ + s] = u.y;
                Vg[((size_t)(bh*DH + d + 2))*SEQ + s] = u.z;
                Vg[((size_t)(bh*DH + d + 3))*SEQ + s] = u.w;
            }
        }
    }
}

// ------- GEMM (N=256) + residual + LayerNorm fused, swapped epilogue ---------
// BM=32, BN=256: block owns 32 full rows. Wave (wr,wc): m = m0+16wr+col,
// n = 128wc + j*16 + quad*4 + r. Row-reduce = lane-local + shfl(16,32) + LDS.
__global__ __launch_bounds__(256) void gemm_ln(
    const unsigned short* __restrict__ A, const unsigned short* __restrict__ B,
    const float* __restrict__ bias, const float* __restrict__ g,
    const float* __restrict__ beta, float* __restrict__ h,
    unsigned short* __restrict__ hb, int K)
{
    __shared__ unsigned short As[32][LDP];
    __shared__ unsigned short Bs[256][LDP];
    __shared__ float sP[2][32], qP[2][32];
    int tid  = threadIdx.x;
    int w    = tid >> 6, lane = tid & 63;
    int col  = lane & 15, quad = lane >> 4;
    int wr   = w >> 1, wc = w & 1;
    int m0   = blockIdx.x * 32;
    int brow = tid >> 2, bch = (tid & 3) * 8;

    f32x4 acc[8];
    #pragma unroll
    for (int j = 0; j < 8; ++j) acc[j] = (f32x4){0.f,0.f,0.f,0.f};

    for (int k0 = 0; k0 < K; k0 += BK) {
        __syncthreads();
        if (tid < 128)
            *(uint4*)&As[tid>>2][bch] = *(const uint4*)(A + (size_t)(m0+(tid>>2))*K + k0 + bch);
        #pragma unroll
        for (int rr = 0; rr < 4; ++rr)
            *(uint4*)&Bs[brow + rr*64][bch] = *(const uint4*)(B + (size_t)(brow + rr*64)*K + k0 + bch);
        __syncthreads();
        bf16x8 af = *(const bf16x8*)&As[16*wr + col][quad*8];
        #pragma unroll
        for (int j = 0; j < 8; ++j) {
            bf16x8 bfr = *(const bf16x8*)&Bs[128*wc + j*16 + col][quad*8];
            acc[j] = __builtin_amdgcn_mfma_f32_16x16x32_bf16(bfr, af, acc[j], 0, 0, 0);
        }
    }

    int m = m0 + 16*wr + col;
    float v[8][4];
    float s = 0.f, q = 0.f;
    #pragma unroll
    for (int j = 0; j < 8; ++j) {
        int n = 128*wc + j*16 + quad*4;
        float4 bi = *(const float4*)&bias[n];
        float4 hv = *(const float4*)&h[(size_t)m*DMODEL + n];
        float val0 = acc[j][0] + bi.x + hv.x;
        float val1 = acc[j][1] + bi.y + hv.y;
        float val2 = acc[j][2] + bi.z + hv.z;
        float val3 = acc[j][3] + bi.w + hv.w;
        v[j][0]=val0; v[j][1]=val1; v[j][2]=val2; v[j][3]=val3;
        s += (val0+val1) + (val2+val3);
        q += (val0*val0 + val1*val1) + (val2*val2 + val3*val3);
    }
    s += __shfl_xor(s, 16, 64); s += __shfl_xor(s, 32, 64);
    q += __shfl_xor(q, 16, 64); q += __shfl_xor(q, 32, 64);
    if (quad == 0) { sP[wc][16*wr + col] = s; qP[wc][16*wr + col] = q; }
    __syncthreads();
    float st = sP[0][16*wr + col] + sP[1][16*wr + col];
    float qt = qP[0][16*wr + col] + qP[1][16*wr + col];
    float mu   = st * (1.0f/DMODEL);
    float var  = qt * (1.0f/DMODEL) - mu*mu;
    float rstd = rsqrtf(var + 1e-5f);
    #pragma unroll
    for (int j = 0; j < 8; ++j) {
        int n = 128*wc + j*16 + quad*4;
        float4 gv = *(const float4*)&g[n];
        float4 bv = *(const float4*)&beta[n];
        float4 o;
        o.x = (v[j][0]-mu)*rstd*gv.x + bv.x;
        o.y = (v[j][1]-mu)*rstd*gv.y + bv.y;
        o.z = (v[j][2]-mu)*rstd*gv.z + bv.z;
        o.w = (v[j][3]-mu)*rstd*gv.w + bv.w;
        *(float4*)&h[(size_t)m*DMODEL + n] = o;
        ushort4 u;
        u.x=(unsigned short)f2bf(o.x); u.y=(unsigned short)f2bf(o.y);
        u.z=(unsigned short)f2bf(o.z); u.w=(unsigned short)f2bf(o.w);
        *(ushort4*)(hb + (size_t)m*DMODEL + n) = u;
    }
}

// ------- head: out = gelu(A@W1^T + b1) . w2 + b2, swapped epilogue -----------
// BM=16, BN=512=DFF. Wave w: m = m0+col, n = 128w + j*16 + quad*4 + r.
__global__ __launch_bounds__(256) void gemm_head(
    const unsigned short* __restrict__ A, const unsigned short* __restrict__ B,
    const float* __restrict__ b1, const float* __restrict__ w2,
    const float* __restrict__ b2, float* __restrict__ out, int K)
{
    __shared__ unsigned short As[16][LDP];
    __shared__ unsigned short Bs[512][LDP];
    __shared__ float dP[4][16];
    int tid  = threadIdx.x;
    int w    = tid >> 6, lane = tid & 63;
    int col  = lane & 15, quad = lane >> 4;
    int m0   = blockIdx.x * 16;
    int brow = tid >> 2, bch = (tid & 3) * 8;

    f32x4 acc[8];
    #pragma unroll
    for (int j = 0; j < 8; ++j) acc[j] = (f32x4){0.f,0.f,0.f,0.f};

    for (int k0 = 0; k0 < K; k0 += BK) {
        __syncthreads();
        if (tid < 64)
            *(uint4*)&As[tid>>2][bch] = *(const uint4*)(A + (size_t)(m0+(tid>>2))*K + k0 + bch);
        #pragma unroll
        for (int rr = 0; rr < 8; ++rr)
            *(uint4*)&Bs[brow + rr*64][bch] = *(const uint4*)(B + (size_t)(brow + rr*64)*K + k0 + bch);
        __syncthreads();
        bf16x8 af = *(const bf16x8*)&As[col][quad*8];
        #pragma unroll
        for (int j = 0; j < 8; ++j) {
            bf16x8 bfr = *(const bf16x8*)&Bs[128*w + j*16 + col][quad*8];
            acc[j] = __builtin_amdgcn_mfma_f32_16x16x32_bf16(bfr, af, acc[j], 0, 0, 0);
        }
    }

    float s = 0.f;
    #pragma unroll
    for (int j = 0; j < 8; ++j) {
        int n = 128*w + j*16 + quad*4;
        float4 b1v = *(const float4*)&b1[n];
        float4 w2v = *(const float4*)&w2[n];
        s += gelu_exact(acc[j][0] + b1v.x) * w2v.x;
        s += gelu_exact(acc[j][1] + b1v.y) * w2v.y;
        s += gelu_exact(acc[j][2] + b1v.z) * w2v.z;
        s += gelu_exact(acc[j][3] + b1v.w) * w2v.w;
    }
    s += __shfl_xor(s, 16, 64); s += __shfl_xor(s, 32, 64);
    if (quad == 0) dP[w][col] = s;
    __syncthreads();
    if (tid < 16)
        out[m0 + tid] = dP[0][tid] + dP[1][tid] + dP[2][tid] + dP[3][tid] + b2[0];
}

// ---------------- MFMA flash attention, transposed flow ----------------------
// Q from Qg [b][h][s][d]; K from Kg [b][h][s][d]; V from Vg [b][h][d][s].
// L accumulated in-register from rounded-bf16 p (matches PV numerics).
__global__ __launch_bounds__(256) void attn_mfma(
    const unsigned short* __restrict__ Qg,
    const unsigned short* __restrict__ Kg,
    const unsigned short* __restrict__ Vg,
    unsigned short* __restrict__ o)           // bf16 [s*B+b][256]
{
    const int qt = blockIdx.x;
    const int h  = blockIdx.y;
    const int b  = blockIdx.z;
    const int q0 = qt * 64;
    const int tid  = threadIdx.x;
    const int w    = tid >> 6;
    const int lane = tid & 63;
    const int col  = lane & 15;
    const int quad = lane >> 4;
    const int bh   = b*NHEAD + h;

    __shared__ unsigned short Kt[64][40];     // [key][d]
    __shared__ unsigned short Vt[32][72];     // [d][key]
    __shared__ unsigned short Pt[4][16][72];  // per-wave P [q][key]

    const int q = q0 + 16*w + col;
    bf16x8 qf = *(const bf16x8*)(Qg + ((size_t)(bh*SEQ + q))*DH + quad*8);

    f32x4 O0 = {0.f,0.f,0.f,0.f};
    f32x4 O1 = {0.f,0.f,0.f,0.f};
    float lsum = 0.f;

    const int kRow = tid >> 2, kCh = (tid & 3) * 8;
    const int vD   = tid >> 3, vCh = (tid & 7) * 8;

    const int nT = 16 + ((q0 >= MPOS) ? 1 : 0);
    for (int kt = 0; kt < nT; ++kt) {
        const bool self = (kt == 16);
        const int  k0   = self ? q0 : kt*64;
        __syncthreads();
        *(uint4*)&Kt[kRow][kCh] = *(const uint4*)(Kg + ((size_t)(bh*SEQ + k0 + kRow))*DH + kCh);
        *(uint4*)&Vt[vD][vCh]   = *(const uint4*)(Vg + ((size_t)(bh*DH + vD))*SEQ + k0 + vCh);
        __syncthreads();

        #pragma unroll
        for (int mt = 0; mt < 4; ++mt) {
            bf16x8 kf = *(const bf16x8*)&Kt[mt*16 + col][quad*8];
            f32x4 st = {0.f,0.f,0.f,0.f};
            st = __builtin_amdgcn_mfma_f32_16x16x32_bf16(kf, qf, st, 0, 0, 0);
            ushort4 pw;
            #pragma unroll
            for (int i = 0; i < 4; ++i) {
                float p = __expf(st[i]*ATT_SCALE);
                if (self && (mt*16 + quad*4 + i != 16*w + col)) p = 0.f;
                unsigned short us = (unsigned short)f2bf(p);
                ((unsigned short*)&pw)[i] = us;
                lsum += bf2f(us);
            }
            *(ushort4*)&Pt[w][col][mt*16 + quad*4] = pw;
        }
        #pragma unroll
        for (int c = 0; c < 2; ++c) {
            bf16x8 pf = *(const bf16x8*)&Pt[w][col][c*32 + quad*8];
            bf16x8 v0 = *(const bf16x8*)&Vt[col     ][c*32 + quad*8];
            bf16x8 v1 = *(const bf16x8*)&Vt[col + 16][c*32 + quad*8];
            O0 = __builtin_amdgcn_mfma_f32_16x16x32_bf16(v0, pf, O0, 0, 0, 0);
            O1 = __builtin_amdgcn_mfma_f32_16x16x32_bf16(v1, pf, O1, 0, 0, 0);
        }
    }

    // L[q=col]: sum partials across the 4 quad groups
    lsum += __shfl_xor(lsum, 16, 64);
    lsum += __shfl_xor(lsum, 32, 64);
    float inv = 1.0f / lsum;
    ushort4 u0, u1;
    #pragma unroll
    for (int i = 0; i < 4; ++i) {
        ((unsigned short*)&u0)[i] = (unsigned short)f2bf(O0[i]*inv);
        ((unsigned short*)&u1)[i] = (unsigned short)f2bf(O1[i]*inv);
    }
    unsigned short* op = o + ((size_t)(q*BATCH + b))*DMODEL + h*DH;
    *(ushort4*)(op + quad*4)      = u0;
    *(ushort4*)(op + 16 + quad*4) = u1;
}

extern "C" void kernel_launch(void* const* d_in, const int* in_sizes, int n_in,
                              void* d_out, int out_size, void* d_ws, size_t ws_size,
                              hipStream_t stream)
{
    const float* x        = (const float*)d_in[0];
    const float* y        = (const float*)d_in[1];
    const float* xenc_w   = (const float*)d_in[3];
    const float* xenc_b   = (const float*)d_in[4];
    const float* yenc_w   = (const float*)d_in[5];
    const float* yenc_b   = (const float*)d_in[6];
    const float* in_proj_w  = (const float*)d_in[7];
    const float* in_proj_b  = (const float*)d_in[8];
    const float* out_proj_w = (const float*)d_in[9];
    const float* out_proj_b = (const float*)d_in[10];
    const float* ln1_g    = (const float*)d_in[11];
    const float* ln1_b    = (const float*)d_in[12];
    const float* lin1_w   = (const float*)d_in[13];
    const float* lin1_b   = (const float*)d_in[14];
    const float* lin2_w   = (const float*)d_in[15];
    const float* lin2_b   = (const float*)d_in[16];
    const float* ln2_g    = (const float*)d_in[17];
    const float* ln2_b    = (const float*)d_in[18];
    const float* head_w1  = (const float*)d_in[19];
    const float* head_b1  = (const float*)d_in[20];
    const float* head_w2  = (const float*)d_in[21];
    const float* head_b2  = (const float*)d_in[22];
    float* out = (float*)d_out;

    // ---- workspace layout ----
    float* ws  = (float*)d_ws;
    float* h    = ws;                                           // 2M f32
    unsigned short* hb    = (unsigned short*)(h + (size_t)ROWS*DMODEL);  // 2M bf16
    unsigned short* ffb   = hb    + (size_t)ROWS*DMODEL;        // 4M bf16
    unsigned short* attb  = ffb   + (size_t)ROWS*DFF;           // 2M bf16
    unsigned short* Qg    = attb  + (size_t)ROWS*DMODEL;        // 2M bf16
    unsigned short* Kg    = Qg    + (size_t)BATCH*NHEAD*SEQ*DH; // 2M bf16
    unsigned short* Vg    = Kg    + (size_t)BATCH*NHEAD*SEQ*DH; // 2M bf16
    unsigned short* Wqkv  = Vg    + (size_t)BATCH*NHEAD*SEQ*DH; // weights bf16
    unsigned short* Wout  = Wqkv  + (size_t)NLAYER*3*DMODEL*DMODEL;
    unsigned short* Wl1   = Wout  + (size_t)NLAYER*DMODEL*DMODEL;
    unsigned short* Wl2   = Wl1   + (size_t)NLAYER*DFF*DMODEL;
    unsigned short* Wh1   = Wl2   + (size_t)NLAYER*DMODEL*DFF;

    encode_cast<<<ROWS + 576, 256, 0, stream>>>(
        x, y, xenc_w, xenc_b, yenc_w, yenc_b, h, hb,
        in_proj_w, out_proj_w, lin1_w, lin2_w, head_w1,
        Wqkv, Wout, Wl1, Wl2, Wh1);

    for (int l = 0; l < NLAYER; ++l) {
        gemm_qkv<<<dim3(6, ROWS/128), 256, 0, stream>>>(
            hb, Wqkv + (size_t)l*3*DMODEL*DMODEL, in_proj_b + l*3*DMODEL,
            Qg, Kg, Vg, DMODEL);
        attn_mfma<<<dim3(SEQ/64, NHEAD, BATCH), 256, 0, stream>>>(Qg, Kg, Vg, attb);
        gemm_ln<<<ROWS/32, 256, 0, stream>>>(
            attb, Wout + (size_t)l*DMODEL*DMODEL, out_proj_b + l*DMODEL,
            ln1_g + l*DMODEL, ln1_b + l*DMODEL, h, hb, DMODEL);
        gemm128<<<dim3(DFF/128, ROWS/128), 256, 0, stream>>>(
            hb, Wl1 + (size_t)l*DFF*DMODEL, lin1_b + l*DFF,
            ffb, DFF, DMODEL, 1);
        gemm_ln<<<ROWS/32, 256, 0, stream>>>(
            ffb, Wl2 + (size_t)l*DMODEL*DFF, lin2_b + l*DMODEL,
            ln2_g + l*DMODEL, ln2_b + l*DMODEL, h, hb, DFF);
    }

    const int QROWS = (SEQ - MPOS) * BATCH;  // 4096
    gemm_head<<<QROWS/16, 256, 0, stream>>>(
        hb + (size_t)MPOS*BATCH*DMODEL, Wh1, head_b1, head_w2, head_b2, out, DMODEL);
}